// Round 1
// baseline (1894.821 us; speedup 1.0000x reference)
//
#include <hip/hip_runtime.h>

typedef float v4f __attribute__((ext_vector_type(4)));

#define BM 128
#define BN 128
#define BK 64

// ---------- fp8 pack helper: 4 f32 -> 4 e4m3 bytes (RNE, HW cvt) ----------
__device__ __forceinline__ unsigned int pack4_fp8(float a, float b, float c, float d) {
    unsigned int v = __builtin_amdgcn_cvt_pk_fp8_f32(a, b, 0, false);   // bytes 0,1
    v = __builtin_amdgcn_cvt_pk_fp8_f32(c, d, v, true);                 // bytes 2,3
    return v;
}

// ---------- 1) quantize input: f32 [M,K] -> e4m3 bytes [M,K] ----------
__global__ __launch_bounds__(256) void quant_x_kernel(
    const float* __restrict__ X, const float* __restrict__ sp,
    unsigned int* __restrict__ Q)
{
    const long i = (long)blockIdx.x * 256 + threadIdx.x;
    const float s = sp[0];
    const float4 v = ((const float4*)X)[i];
    const float a = fminf(fmaxf(v.x / s, -448.f), 448.f);
    const float b = fminf(fmaxf(v.y / s, -448.f), 448.f);
    const float c = fminf(fmaxf(v.z / s, -448.f), 448.f);
    const float d = fminf(fmaxf(v.w / s, -448.f), 448.f);
    Q[i] = pack4_fp8(a, b, c, d);
}

// ---------- 2) weight: f32 [K,N] (values already on e4m3 grid) -> e4m3 [N,K] (transposed) ----------
// block = 256 threads handles a 64(k) x 64(n) tile; each thread emits 16 contiguous k-bytes of one n-row
__global__ __launch_bounds__(256) void quant_wT_kernel(
    const float* __restrict__ Wf, unsigned char* __restrict__ Wq, int K, int N)
{
    const int k0 = blockIdx.x * 64;
    const int n0 = blockIdx.y * 64;
    const int t  = threadIdx.x;
    const int n  = t >> 2;          // 0..63
    const int kc = (t & 3) * 16;    // 0,16,32,48
    const float* src = Wf + (long)(k0 + kc) * N + n0 + n;
    unsigned int o[4];
#pragma unroll
    for (int j = 0; j < 4; ++j) {
        const float x0 = src[(long)(4 * j + 0) * N];
        const float x1 = src[(long)(4 * j + 1) * N];
        const float x2 = src[(long)(4 * j + 2) * N];
        const float x3 = src[(long)(4 * j + 3) * N];
        o[j] = pack4_fp8(x0, x1, x2, x3);   // exact: inputs are on the fp8 grid
    }
    uint4 q; q.x = o[0]; q.y = o[1]; q.z = o[2]; q.w = o[3];
    *(uint4*)(Wq + (long)(n0 + n) * K + k0 + kc) = q;
}

// ---------- async 16B global -> LDS ----------
__device__ __forceinline__ void async_copy16(const void* g, void* l) {
    __builtin_amdgcn_global_load_lds(
        (const __attribute__((address_space(1))) unsigned int*)g,
        (__attribute__((address_space(3))) unsigned int*)l,
        16, 0, 0);
}

// ---------- 3) fp8 GEMM: C[M,N] = (A8[M,K] . B8[N,K]^T) * s + bias ----------
// 128x128 block tile, BK=64 bytes, 4 waves in 2x2, each wave 64x64 via 4x4 mfma_f32_16x16x32_fp8_fp8
__global__ __launch_bounds__(256) void fp8_gemm_kernel(
    const unsigned char* __restrict__ A8,   // [M,K] e4m3
    const unsigned char* __restrict__ B8,   // [N,K] e4m3 (pre-transposed)
    const float* __restrict__ bias,
    const float* __restrict__ ws_p, const float* __restrict__ is_p,
    float* __restrict__ C, int M, int N, int K)
{
    __shared__ unsigned long long As[BM * BK / 8];   // 8 KB, row-major [128][64B]
    __shared__ unsigned long long Bs[BN * BK / 8];   // 8 KB, row-major [128][64B]

    const int tid = threadIdx.x;
    const int l   = tid & 63;
    const int w   = tid >> 6;
    const int wr  = w >> 1, wc = w & 1;     // 2x2 wave grid
    const int lm  = l & 15, lg = l >> 4;    // mfma lane decomposition

    const long m0 = (long)blockIdx.y * BM;
    const long n0 = (long)blockIdx.x * BN;

    // staging: one 16B chunk per lane; 256 threads cover 64 rows x 64B per issue
    const unsigned char* aG = A8 + (m0 + (tid >> 2)) * (long)K + (tid & 3) * 16;
    const unsigned char* bG = B8 + (n0 + (tid >> 2)) * (long)K + (tid & 3) * 16;
    const long rowStep = (long)64 * K;

    unsigned char* AsB = (unsigned char*)As;
    unsigned char* BsB = (unsigned char*)Bs;

    v4f acc[4][4];
#pragma unroll
    for (int i = 0; i < 4; ++i)
#pragma unroll
        for (int j = 0; j < 4; ++j)
            acc[i][j] = (v4f){0.f, 0.f, 0.f, 0.f};

    for (int kt = 0; kt < K; kt += BK) {
        async_copy16(aG + kt,           AsB + tid * 16);
        async_copy16(aG + kt + rowStep, AsB + 4096 + tid * 16);
        async_copy16(bG + kt,           BsB + tid * 16);
        async_copy16(bG + kt + rowStep, BsB + 4096 + tid * 16);
        __syncthreads();   // compiler drains vmcnt before s_barrier

#pragma unroll
        for (int kk = 0; kk < 2; ++kk) {
            long af[4], bf[4];
#pragma unroll
            for (int mt = 0; mt < 4; ++mt)
                af[mt] = (long)As[(wr * 64 + mt * 16 + lm) * 8 + kk * 4 + lg];
#pragma unroll
            for (int nt = 0; nt < 4; ++nt)
                bf[nt] = (long)Bs[(wc * 64 + nt * 16 + lm) * 8 + kk * 4 + lg];
#pragma unroll
            for (int mt = 0; mt < 4; ++mt)
#pragma unroll
                for (int nt = 0; nt < 4; ++nt)
                    acc[mt][nt] = __builtin_amdgcn_mfma_f32_16x16x32_fp8_fp8(
                        af[mt], bf[nt], acc[mt][nt], 0, 0, 0);
        }
        __syncthreads();
    }

    // epilogue: C/D layout col = lane&15, row = (lane>>4)*4 + reg
    const float s = is_p[0] * ws_p[0];
#pragma unroll
    for (int nt = 0; nt < 4; ++nt) {
        const long c = n0 + wc * 64 + nt * 16 + lm;
        const float bv = bias[c];
#pragma unroll
        for (int mt = 0; mt < 4; ++mt) {
            const long r = m0 + wr * 64 + mt * 16 + lg * 4;
            float* dst = C + r * (long)N + c;
#pragma unroll
            for (int i = 0; i < 4; ++i)
                dst[(long)i * N] = acc[mt][nt][i] * s + bv;
        }
    }
}

extern "C" void kernel_launch(void* const* d_in, const int* in_sizes, int n_in,
                              void* d_out, int out_size, void* d_ws, size_t ws_size,
                              hipStream_t stream)
{
    const float* X    = (const float*)d_in[0];   // [M,K] f32
    const float* Wf   = (const float*)d_in[1];   // [K,N] f32 (fp8-grid values)
    const float* bias = (const float*)d_in[2];   // [N] f32
    const float* wsc  = (const float*)d_in[3];   // weight_scale
    const float* isc  = (const float*)d_in[4];   // input_scale
    float* out = (float*)d_out;

    const int N = in_sizes[2];
    const int K = in_sizes[1] / N;
    const int M = in_sizes[0] / K;

    unsigned char* A8 = (unsigned char*)d_ws;            // M*K bytes
    unsigned char* B8 = A8 + (size_t)M * K;              // N*K bytes

    // 1) input quant: M*K/4 uint words
    quant_x_kernel<<<dim3((unsigned)((long)M * K / 4 / 256)), 256, 0, stream>>>(
        X, isc, (unsigned int*)A8);

    // 2) weight quant + transpose
    quant_wT_kernel<<<dim3(K / 64, N / 64), 256, 0, stream>>>(Wf, B8, K, N);

    // 3) GEMM + scale + bias
    fp8_gemm_kernel<<<dim3(N / BN, M / BM), 256, 0, stream>>>(
        A8, B8, bias, wsc, isc, out, M, N, K);
}

// Round 2
// 1236.208 us; speedup vs baseline: 1.5328x; 1.5328x over previous
//
#include <hip/hip_runtime.h>

typedef float v4f __attribute__((ext_vector_type(4)));
typedef unsigned long long u64x2 __attribute__((ext_vector_type(2)));

#define BM 128
#define BN 128
#define BK 64

// ---------- fp8 pack helper: 4 f32 -> 4 e4m3 bytes (RNE, HW cvt) ----------
__device__ __forceinline__ unsigned int pack4_fp8(float a, float b, float c, float d) {
    unsigned int v = __builtin_amdgcn_cvt_pk_fp8_f32(a, b, 0, false);   // bytes 0,1
    v = __builtin_amdgcn_cvt_pk_fp8_f32(c, d, v, true);                 // bytes 2,3
    return v;
}

// ---------- 1) quantize input: f32 [M,K] -> e4m3 bytes [M,K] ----------
__global__ __launch_bounds__(256) void quant_x_kernel(
    const float* __restrict__ X, const float* __restrict__ sp,
    unsigned int* __restrict__ Q)
{
    const long i = (long)blockIdx.x * 256 + threadIdx.x;
    const float s = sp[0];
    const float4 v = ((const float4*)X)[i];
    const float a = fminf(fmaxf(v.x / s, -448.f), 448.f);
    const float b = fminf(fmaxf(v.y / s, -448.f), 448.f);
    const float c = fminf(fmaxf(v.z / s, -448.f), 448.f);
    const float d = fminf(fmaxf(v.w / s, -448.f), 448.f);
    Q[i] = pack4_fp8(a, b, c, d);
}

// ---------- 2) weight: f32 [K,N] (values already on e4m3 grid) -> e4m3 [N,K] (transposed) ----------
__global__ __launch_bounds__(256) void quant_wT_kernel(
    const float* __restrict__ Wf, unsigned char* __restrict__ Wq, int K, int N)
{
    const int k0 = blockIdx.x * 64;
    const int n0 = blockIdx.y * 64;
    const int t  = threadIdx.x;
    const int n  = t >> 2;          // 0..63
    const int kc = (t & 3) * 16;    // 0,16,32,48
    const float* src = Wf + (long)(k0 + kc) * N + n0 + n;
    unsigned int o[4];
#pragma unroll
    for (int j = 0; j < 4; ++j) {
        const float x0 = src[(long)(4 * j + 0) * N];
        const float x1 = src[(long)(4 * j + 1) * N];
        const float x2 = src[(long)(4 * j + 2) * N];
        const float x3 = src[(long)(4 * j + 3) * N];
        o[j] = pack4_fp8(x0, x1, x2, x3);   // exact: inputs are on the fp8 grid
    }
    uint4 q; q.x = o[0]; q.y = o[1]; q.z = o[2]; q.w = o[3];
    *(uint4*)(Wq + (long)(n0 + n) * K + k0 + kc) = q;
}

// ---------- async 16B global -> LDS ----------
__device__ __forceinline__ void async_copy16(const void* g, void* l) {
    __builtin_amdgcn_global_load_lds(
        (const __attribute__((address_space(1))) unsigned int*)g,
        (__attribute__((address_space(3))) unsigned int*)l,
        16, 0, 0);
}

// ---------- 3) fp8 GEMM: C[M,N] = (A8[M,K] . B8[N,K]^T) * s + bias ----------
// 128x128 block tile, BK=64 bytes, 4 waves in 2x2, each wave 64x64 via 4x4 mfma_f32_16x16x32_fp8_fp8.
// k-interleave trick: the two MFMAs per 64B k-tile consume k-slices
//   kk=0: orig bytes [lg*16, lg*16+8), kk=1: [lg*16+8, lg*16+16)   (same perm for A and B
//   => dot product unchanged). This makes each lane's both-kk fragment one contiguous
//   ds_read_b128 at row*64 + lg*16 -> bank (lm&1)*16+lg*4 -> all 32 banks hit exactly 8x
//   = conflict-free minimum (vs 8-way-conflicted ds_read_b64 before).
__global__ __launch_bounds__(256) void fp8_gemm_kernel(
    const unsigned char* __restrict__ A8,   // [M,K] e4m3
    const unsigned char* __restrict__ B8,   // [N,K] e4m3 (pre-transposed)
    const float* __restrict__ bias,
    const float* __restrict__ ws_p, const float* __restrict__ is_p,
    float* __restrict__ C, int M, int N, int K)
{
    __shared__ unsigned long long As[BM * BK / 8];   // 8 KB, row-major [128][64B]
    __shared__ unsigned long long Bs[BN * BK / 8];   // 8 KB, row-major [128][64B]

    const int tid = threadIdx.x;
    const int l   = tid & 63;
    const int w   = tid >> 6;
    const int wr  = w >> 1, wc = w & 1;     // 2x2 wave grid
    const int lm  = l & 15, lg = l >> 4;    // mfma lane decomposition

    const long m0 = (long)blockIdx.y * BM;
    const long n0 = (long)blockIdx.x * BN;

    // staging: one 16B chunk per lane; 256 threads cover 64 rows x 64B per issue
    const unsigned char* aG = A8 + (m0 + (tid >> 2)) * (long)K + (tid & 3) * 16;
    const unsigned char* bG = B8 + (n0 + (tid >> 2)) * (long)K + (tid & 3) * 16;
    const long rowStep = (long)64 * K;

    unsigned char* AsB = (unsigned char*)As;
    unsigned char* BsB = (unsigned char*)Bs;
    const u64x2* As2 = (const u64x2*)As;    // 16B units
    const u64x2* Bs2 = (const u64x2*)Bs;

    v4f acc[4][4];
#pragma unroll
    for (int i = 0; i < 4; ++i)
#pragma unroll
        for (int j = 0; j < 4; ++j)
            acc[i][j] = (v4f){0.f, 0.f, 0.f, 0.f};

    for (int kt = 0; kt < K; kt += BK) {
        async_copy16(aG + kt,           AsB + tid * 16);
        async_copy16(aG + kt + rowStep, AsB + 4096 + tid * 16);
        async_copy16(bG + kt,           BsB + tid * 16);
        async_copy16(bG + kt + rowStep, BsB + 4096 + tid * 16);
        __syncthreads();   // compiler drains vmcnt before s_barrier

        u64x2 a[4], b[4];
#pragma unroll
        for (int mt = 0; mt < 4; ++mt)
            a[mt] = As2[(wr * 64 + mt * 16 + lm) * 4 + lg];
#pragma unroll
        for (int nt = 0; nt < 4; ++nt)
            b[nt] = Bs2[(wc * 64 + nt * 16 + lm) * 4 + lg];

#pragma unroll
        for (int mt = 0; mt < 4; ++mt)
#pragma unroll
            for (int nt = 0; nt < 4; ++nt) {
                acc[mt][nt] = __builtin_amdgcn_mfma_f32_16x16x32_fp8_fp8(
                    (long)a[mt][0], (long)b[nt][0], acc[mt][nt], 0, 0, 0);
                acc[mt][nt] = __builtin_amdgcn_mfma_f32_16x16x32_fp8_fp8(
                    (long)a[mt][1], (long)b[nt][1], acc[mt][nt], 0, 0, 0);
            }
        __syncthreads();
    }

    // epilogue: C/D layout col = lane&15, row = (lane>>4)*4 + reg
    const float s = is_p[0] * ws_p[0];
#pragma unroll
    for (int nt = 0; nt < 4; ++nt) {
        const long c = n0 + wc * 64 + nt * 16 + lm;
        const float bv = bias[c];
#pragma unroll
        for (int mt = 0; mt < 4; ++mt) {
            const long r = m0 + wr * 64 + mt * 16 + lg * 4;
            float* dst = C + r * (long)N + c;
#pragma unroll
            for (int i = 0; i < 4; ++i)
                dst[(long)i * N] = acc[mt][nt][i] * s + bv;
        }
    }
}

extern "C" void kernel_launch(void* const* d_in, const int* in_sizes, int n_in,
                              void* d_out, int out_size, void* d_ws, size_t ws_size,
                              hipStream_t stream)
{
    const float* X    = (const float*)d_in[0];   // [M,K] f32
    const float* Wf   = (const float*)d_in[1];   // [K,N] f32 (fp8-grid values)
    const float* bias = (const float*)d_in[2];   // [N] f32
    const float* wsc  = (const float*)d_in[3];   // weight_scale
    const float* isc  = (const float*)d_in[4];   // input_scale
    float* out = (float*)d_out;

    const int N = in_sizes[2];
    const int K = in_sizes[1] / N;
    const int M = in_sizes[0] / K;

    unsigned char* A8 = (unsigned char*)d_ws;            // M*K bytes
    unsigned char* B8 = A8 + (size_t)M * K;              // N*K bytes

    // 1) input quant: M*K/4 uint words
    quant_x_kernel<<<dim3((unsigned)((long)M * K / 4 / 256)), 256, 0, stream>>>(
        X, isc, (unsigned int*)A8);

    // 2) weight quant + transpose
    quant_wT_kernel<<<dim3(K / 64, N / 64), 256, 0, stream>>>(Wf, B8, K, N);

    // 3) GEMM + scale + bias
    fp8_gemm_kernel<<<dim3(N / BN, M / BM), 256, 0, stream>>>(
        A8, B8, bias, wsc, isc, out, M, N, K);
}